// Round 1
// baseline (40622.714 us; speedup 1.0000x reference)
//
#include <hip/hip_runtime.h>
#include <cstdint>

#define T_STEPS 2048
#define GROUPS 8
#define BPG 16      // batches per group
#define HS 25       // hidden slices (wgs per group)
#define HU 16       // hidden units per wg
#define NCOL 64     // gate columns per wg (4 gates x HU)
#define KTOT 404    // 400 hidden + 4 input
#define WROW 424    // LDS weight row pitch (bf16 elems), padded vs bank conflicts
#define HROW 416    // h buffer row pitch (bf16 elems) = 13*32
#define KCH 13      // K chunks of 32

typedef float f32x4 __attribute__((ext_vector_type(4)));
typedef short s16x8 __attribute__((ext_vector_type(8)));

__device__ __forceinline__ unsigned short f2bf(float f) {
  unsigned int u = __float_as_uint(f);
  unsigned int r = (u + 0x7FFFu + ((u >> 16) & 1u)) >> 16;
  return (unsigned short)r;
}
__device__ __forceinline__ float sigm(float x) { return 1.0f / (1.0f + __expf(-x)); }
__device__ __forceinline__ float tanh_f(float x) { return 1.0f - 2.0f / (__expf(2.0f * x) + 1.0f); }

// ---------------------------------------------------------------------------
// Encoder LSTM: persistent flag-synced recurrence.
// grid = 200 (8 batch-groups x 25 hidden-slices), block = 256.
// ---------------------------------------------------------------------------
__global__ __launch_bounds__(256, 1) void enc_kernel(
    const float* __restrict__ x, const float* __restrict__ W_hh,
    const float* __restrict__ W_ih, const float* __restrict__ b_enc,
    unsigned short* __restrict__ hbuf, float* __restrict__ last_h,
    int* __restrict__ flags)
{
  __shared__ unsigned short Wl[NCOL * WROW];
  __shared__ float bias_l[NCOL];
  __shared__ float gates[4][BPG][HU];
  __shared__ float cstate[BPG][HU];

  const int tid = threadIdx.x;
  const int g = blockIdx.x & 7;    // batch group (XCD-affine)
  const int n = blockIdx.x >> 3;   // hidden slice 0..24
  const int bbase = g * BPG;
  const int hbase = n * HU;

  // --- stage weights into LDS (bf16), K layout: [0,400)=W_hh row, [400,404)=W_ih row, rest 0
  for (int idx = tid; idx < NCOL * 101; idx += 256) {
    int c = idx / 101, kq = idx % 101;
    int gt = c >> 4, u = c & 15;
    int row = gt * 400 + hbase + u;
    int k0 = kq * 4;
    float4 w;
    if (k0 < 400) w = *(const float4*)(W_hh + (size_t)row * 400 + k0);
    else          w = *(const float4*)(W_ih + (size_t)row * 4);
    unsigned short* dst = Wl + c * WROW + k0;
    dst[0] = f2bf(w.x); dst[1] = f2bf(w.y); dst[2] = f2bf(w.z); dst[3] = f2bf(w.w);
  }
  for (int idx = tid; idx < NCOL * (WROW - KTOT); idx += 256) {
    int c = idx / (WROW - KTOT), kk = KTOT + idx % (WROW - KTOT);
    Wl[c * WROW + kk] = 0;
  }
  if (tid < NCOL) {
    int gt = tid >> 4, u = tid & 15;
    bias_l[tid] = b_enc[gt * 400 + hbase + u];
  }
  cstate[tid >> 4][tid & 15] = 0.f;
  // x_0 into parity-0 buffer (h part is zero from host-side memset)
  if (n == 0 && tid < BPG) {
    float4 xv = *(const float4*)(x + (size_t)(bbase + tid) * T_STEPS * 4);
    unsigned short* d = hbuf + (size_t)(bbase + tid) * HROW + 400;
    d[0] = f2bf(xv.x); d[1] = f2bf(xv.y); d[2] = f2bf(xv.z); d[3] = f2bf(xv.w);
  }
  __syncthreads();
  if (tid == 0) {
    __threadfence();
    __hip_atomic_store(&flags[(g * HS + n) * 16], 1, __ATOMIC_RELEASE, __HIP_MEMORY_SCOPE_AGENT);
  }

  const int wave = tid >> 6, lane = tid & 63;
  const int arow = lane & 15, kgrp = lane >> 4;
  const unsigned short* Bbase = Wl + (wave * 16 + arow) * WROW + kgrp * 8;
  int* fl = flags + g * HS * 16;
  const int myflag = (g * HS + n) * 16;

  for (int t = 0; t < T_STEPS; ++t) {
    const int p = t & 1;
    // prefetch next x (n==0 only), hidden under poll + K-loop
    float4 xn;
    const bool do_x = (n == 0) && (tid < BPG) && (t + 1 < T_STEPS);
    if (do_x) xn = *(const float4*)(x + ((size_t)(bbase + tid) * T_STEPS + (t + 1)) * 4);

    // --- wait for all 25 slices of this group's h_t
    {
      const int target = t + 1;
      while (true) {
        int fv = 0x7fffffff;
        if (lane < HS)
          fv = __hip_atomic_load(&fl[lane * 16], __ATOMIC_ACQUIRE, __HIP_MEMORY_SCOPE_AGENT);
        if (__all(fv >= target)) break;
      }
    }

    // --- GEMM: gates[16 batches x 64 cols] over K=416
    const unsigned short* Arow = hbuf + ((size_t)p * 128 + (bbase + arow)) * HROW + kgrp * 8;
    f32x4 acc = {0.f, 0.f, 0.f, 0.f};
#pragma unroll
    for (int kc = 0; kc < KCH; ++kc) {
      s16x8 a = *(const s16x8*)(Arow + kc * 32);
      s16x8 b = *(const s16x8*)(Bbase + kc * 32);
      acc = __builtin_amdgcn_mfma_f32_16x16x32_bf16(a, b, acc, 0, 0, 0);
    }
#pragma unroll
    for (int r = 0; r < 4; ++r)
      gates[wave][kgrp * 4 + r][arow] = acc[r];
    __syncthreads();

    // --- elementwise gate update; each thread owns one (batch, hidden)
    {
      const int b = tid >> 4, u = tid & 15;
      float gi = gates[0][b][u] + bias_l[u];
      float gf = gates[1][b][u] + bias_l[16 + u];
      float gg = gates[2][b][u] + bias_l[32 + u];
      float go = gates[3][b][u] + bias_l[48 + u];
      float cn = sigm(gf) * cstate[b][u] + sigm(gi) * tanh_f(gg);
      float hn = sigm(go) * tanh_f(cn);
      cstate[b][u] = cn;
      hbuf[((size_t)(p ^ 1) * 128 + (bbase + b)) * HROW + hbase + u] = f2bf(hn);
      if (t == T_STEPS - 1) last_h[(size_t)(bbase + b) * 400 + hbase + u] = hn;
    }
    if (do_x) {
      unsigned short* d = hbuf + ((size_t)(p ^ 1) * 128 + (bbase + tid)) * HROW + 400;
      d[0] = f2bf(xn.x); d[1] = f2bf(xn.y); d[2] = f2bf(xn.z); d[3] = f2bf(xn.w);
    }
    __syncthreads();
    if (tid == 0) {
      __threadfence();
      __hip_atomic_store(&flags[myflag], t + 2, __ATOMIC_RELEASE, __HIP_MEMORY_SCOPE_AGENT);
    }
  }
}

// ---------------------------------------------------------------------------
// Decoder input precompute: uw[b,t,16] = relu(x W_i2h^T + b_i2h) W_dec_ih^T + b_dec
// grid = 512, block = 256, 2 positions per thread.
// ---------------------------------------------------------------------------
__global__ __launch_bounds__(256) void uw_kernel(
    const float* __restrict__ x, const float* __restrict__ W_i2h,
    const float* __restrict__ b_i2h, const float* __restrict__ W_dec,
    const float* __restrict__ b_dec, float* __restrict__ uw)
{
  __shared__ float4 Wi[400];
  __shared__ float4 WdT[400][4];
  __shared__ float bi[400];
  __shared__ float bd[16];
  const int tid = threadIdx.x;
  for (int i = tid; i < 400; i += 256) {
    Wi[i] = *(const float4*)(W_i2h + (size_t)i * 4);
    bi[i] = b_i2h[i];
  }
  for (int i = tid; i < 6400; i += 256) {
    int gq = i & 15, hh = i >> 4;
    ((float*)&WdT[hh][0])[gq] = W_dec[(size_t)gq * 400 + hh];
  }
  if (tid < 16) bd[tid] = b_dec[tid];
  __syncthreads();

  const size_t base = ((size_t)blockIdx.x * 256 + tid) * 2;
  float4 xv0 = *(const float4*)(x + base * 4);
  float4 xv1 = *(const float4*)(x + base * 4 + 4);
  float a0[16], a1[16];
#pragma unroll
  for (int q = 0; q < 16; ++q) { a0[q] = bd[q]; a1[q] = bd[q]; }
  for (int hh = 0; hh < 400; ++hh) {
    float4 wv = Wi[hh];
    float bih = bi[hh];
    float u0 = fmaxf(wv.x * xv0.x + wv.y * xv0.y + wv.z * xv0.z + wv.w * xv0.w + bih, 0.f);
    float u1 = fmaxf(wv.x * xv1.x + wv.y * xv1.y + wv.z * xv1.z + wv.w * xv1.w + bih, 0.f);
#pragma unroll
    for (int q4 = 0; q4 < 4; ++q4) {
      float4 d = WdT[hh][q4];
      a0[q4 * 4 + 0] = fmaf(d.x, u0, a0[q4 * 4 + 0]);
      a0[q4 * 4 + 1] = fmaf(d.y, u0, a0[q4 * 4 + 1]);
      a0[q4 * 4 + 2] = fmaf(d.z, u0, a0[q4 * 4 + 2]);
      a0[q4 * 4 + 3] = fmaf(d.w, u0, a0[q4 * 4 + 3]);
      a1[q4 * 4 + 0] = fmaf(d.x, u1, a1[q4 * 4 + 0]);
      a1[q4 * 4 + 1] = fmaf(d.y, u1, a1[q4 * 4 + 1]);
      a1[q4 * 4 + 2] = fmaf(d.z, u1, a1[q4 * 4 + 2]);
      a1[q4 * 4 + 3] = fmaf(d.w, u1, a1[q4 * 4 + 3]);
    }
  }
  float4* o0 = (float4*)(uw + base * 16);
  float4* o1 = (float4*)(uw + base * 16 + 16);
#pragma unroll
  for (int q4 = 0; q4 < 4; ++q4) {
    o0[q4] = make_float4(a0[q4 * 4], a0[q4 * 4 + 1], a0[q4 * 4 + 2], a0[q4 * 4 + 3]);
    o1[q4] = make_float4(a1[q4 * 4], a1[q4 * 4 + 1], a1[q4 * 4 + 2], a1[q4 * 4 + 3]);
  }
}

// ---------------------------------------------------------------------------
// Head: mu, logvar, z, decoder h0. grid = 128 (one per batch), block = 64.
// ---------------------------------------------------------------------------
__global__ __launch_bounds__(64) void head_kernel(
    const float* __restrict__ last_h, const float* __restrict__ eps,
    const float* __restrict__ W_mu, const float* __restrict__ b_mu,
    const float* __restrict__ W_lv, const float* __restrict__ b_lv,
    const float* __restrict__ W_l2h, const float* __restrict__ b_l2h,
    float* __restrict__ out, float* __restrict__ hd0)
{
  const int b = blockIdx.x, tid = threadIdx.x;
  __shared__ float smu[20], slv[20], sz[20];
  const float4* h4 = (const float4*)(last_h + (size_t)b * 400);
  if (tid < 40) {
    const int o = tid % 20;
    const float4* w4 = (const float4*)((tid < 20 ? W_mu : W_lv) + (size_t)o * 400);
    float s = 0.f;
    for (int k = 0; k < 100; ++k) {
      float4 a = h4[k], w = w4[k];
      s += a.x * w.x + a.y * w.y + a.z * w.z + a.w * w.w;
    }
    if (tid < 20) { s += b_mu[o]; smu[o] = s; out[512 + b * 20 + o] = s; }
    else          { s += b_lv[o]; slv[o] = s; out[512 + 2560 + b * 20 + o] = s; }
  }
  __syncthreads();
  if (tid < 20) sz[tid] = smu[tid] + eps[b * 20 + tid] * __expf(0.5f * slv[tid]);
  __syncthreads();
  if (tid < 4) {
    float s = b_l2h[tid];
    for (int l = 0; l < 20; ++l) s += W_l2h[tid * 20 + l] * sz[l];
    hd0[b * 4 + tid] = s;
  }
}

// ---------------------------------------------------------------------------
// Decoder LSTM: hidden=4, 4 lanes per batch. grid = 2, block = 256.
// ---------------------------------------------------------------------------
__global__ __launch_bounds__(256) void dec_kernel(
    const float* __restrict__ uw, const float* __restrict__ hd0,
    const float* __restrict__ Whh, float* __restrict__ out)
{
  const int t0 = blockIdx.x * 256 + threadIdx.x;
  const int b = t0 >> 2, j = t0 & 3;
  float w[4][4];
#pragma unroll
  for (int gq = 0; gq < 4; ++gq)
#pragma unroll
    for (int k = 0; k < 4; ++k)
      w[gq][k] = Whh[(gq * 4 + j) * 4 + k];
  float h = hd0[b * 4 + j], c = 0.f;
  const float* up = uw + (size_t)b * T_STEPS * 16 + j;
  float n0 = up[0], n1 = up[4], n2 = up[8], n3 = up[12];
  for (int t = 0; t < T_STEPS; ++t) {
    float c0 = n0, c1 = n1, c2 = n2, c3 = n3;
    if (t + 1 < T_STEPS) {
      const float* u2 = up + (size_t)(t + 1) * 16;
      n0 = u2[0]; n1 = u2[4]; n2 = u2[8]; n3 = u2[12];
    }
    float h0 = __shfl(h, 0, 4), h1 = __shfl(h, 1, 4), h2 = __shfl(h, 2, 4), h3 = __shfl(h, 3, 4);
    c0 += w[0][0] * h0 + w[0][1] * h1 + w[0][2] * h2 + w[0][3] * h3;
    c1 += w[1][0] * h0 + w[1][1] * h1 + w[1][2] * h2 + w[1][3] * h3;
    c2 += w[2][0] * h0 + w[2][1] * h1 + w[2][2] * h2 + w[2][3] * h3;
    c3 += w[3][0] * h0 + w[3][1] * h1 + w[3][2] * h2 + w[3][3] * h3;
    c = sigm(c1) * c + sigm(c0) * tanh_f(c2);
    h = sigm(c3) * tanh_f(c);
  }
  out[b * 4 + j] = h;
}

// ---------------------------------------------------------------------------
// ws layout (bytes):
//   [0,      16384)  flags (200 x 64B-strided ints)
//   [16384,  229376) hbuf: 2 x 128 x 416 bf16
//   [229376, 434176) last_h: 128 x 400 f32
//   [434176, 436224) hd0: 128 x 4 f32
//   [524288, 17301504) uw: 128 x 2048 x 16 f32
// ---------------------------------------------------------------------------
extern "C" void kernel_launch(void* const* d_in, const int* in_sizes, int n_in,
                              void* d_out, int out_size, void* d_ws, size_t ws_size,
                              hipStream_t stream)
{
  (void)in_sizes; (void)n_in; (void)out_size; (void)ws_size;
  const float* x        = (const float*)d_in[0];
  const float* eps      = (const float*)d_in[1];
  const float* W_enc_ih = (const float*)d_in[2];
  const float* W_enc_hh = (const float*)d_in[3];
  const float* b_enc    = (const float*)d_in[4];
  const float* W_mu     = (const float*)d_in[5];
  const float* b_mu     = (const float*)d_in[6];
  const float* W_lv     = (const float*)d_in[7];
  const float* b_lv     = (const float*)d_in[8];
  const float* W_l2h    = (const float*)d_in[9];
  const float* b_l2h    = (const float*)d_in[10];
  const float* W_i2h    = (const float*)d_in[11];
  const float* b_i2h    = (const float*)d_in[12];
  const float* W_dec_ih = (const float*)d_in[13];
  const float* W_dec_hh = (const float*)d_in[14];
  const float* b_dec    = (const float*)d_in[15];
  float* out = (float*)d_out;
  char* ws = (char*)d_ws;
  int* flags = (int*)ws;
  unsigned short* hbuf = (unsigned short*)(ws + 16384);
  float* last_h = (float*)(ws + 229376);
  float* hd0 = (float*)(ws + 434176);
  float* uw = (float*)(ws + 524288);

  hipMemsetAsync(ws, 0, 229376, stream);                      // flags + h_0 zeros
  uw_kernel<<<512, 256, 0, stream>>>(x, W_i2h, b_i2h, W_dec_ih, b_dec, uw);
  enc_kernel<<<200, 256, 0, stream>>>(x, W_enc_hh, W_enc_ih, b_enc, hbuf, last_h, flags);
  head_kernel<<<128, 64, 0, stream>>>(last_h, eps, W_mu, b_mu, W_lv, b_lv, W_l2h, b_l2h, out, hd0);
  dec_kernel<<<2, 256, 0, stream>>>(uw, hd0, W_dec_hh, out);
}

// Round 2
// 12403.872 us; speedup vs baseline: 3.2750x; 3.2750x over previous
//
#include <hip/hip_runtime.h>
#include <cstdint>

#define T_STEPS 2048
#define GROUPS 8
#define BPG 16      // batches per group
#define HS 10       // hidden slices (wgs per group)
#define HU 40       // hidden units per wg
#define NCOL 160    // gate columns per wg (4 gates x HU)
#define KTOT 404    // 400 hidden + 4 input
#define WROW 424    // LDS weight row pitch (bf16 elems)
#define HROW 416    // h buffer row pitch (bf16 elems) = 13*32
#define KCH 13      // K chunks of 32
#define GPITCH 17   // gates LDS pitch (f32) - conflict-free

typedef float f32x4 __attribute__((ext_vector_type(4)));
typedef short s16x8 __attribute__((ext_vector_type(8)));

__device__ __forceinline__ unsigned short f2bf(float f) {
  unsigned int u = __float_as_uint(f);
  unsigned int r = (u + 0x7FFFu + ((u >> 16) & 1u)) >> 16;
  return (unsigned short)r;
}
__device__ __forceinline__ float sigm(float x) { return 1.0f / (1.0f + __expf(-x)); }
__device__ __forceinline__ float tanh_f(float x) { return 1.0f - 2.0f / (__expf(2.0f * x) + 1.0f); }

// ---------------------------------------------------------------------------
// Encoder LSTM: persistent recurrence, aggregated-counter sync.
// grid = 80 (8 batch-groups x 10 hidden-slices), block = 640 (10 waves).
// Dynamic LDS: weights 135680 + bias 640 + gates 10880 + cstate 2560 = 149760 B
// ---------------------------------------------------------------------------
__global__ __launch_bounds__(640, 1) void enc_kernel(
    const float* __restrict__ x, const float* __restrict__ W_hh,
    const float* __restrict__ W_ih, const float* __restrict__ b_enc,
    unsigned short* __restrict__ hbuf, float* __restrict__ last_h,
    int* __restrict__ flags)
{
  extern __shared__ char smem[];
  unsigned short* Wl = (unsigned short*)smem;              // [NCOL][WROW]
  float* bias_l = (float*)(smem + 135680);                 // [NCOL]
  float* gatesF = (float*)(smem + 136320);                 // [NCOL][GPITCH]
  float* cstate = (float*)(smem + 147200);                 // [640] = [16][40]

  const int tid = threadIdx.x;
  const int g = blockIdx.x & 7;    // batch group (XCD-affine under round-robin)
  const int n = blockIdx.x >> 3;   // hidden slice 0..9
  const int bbase = g * BPG;
  const int hbase = n * HU;

  // --- stage weights into LDS (bf16). K layout per col: [0,400)=W_hh, [400,404)=W_ih, [404,424)=0
  for (int idx = tid; idx < NCOL * 101; idx += 640) {
    int c = idx / 101, kq = idx % 101;
    int gt = c / HU, u = c % HU;
    int row = gt * 400 + hbase + u;
    int k0 = kq * 4;
    float4 w;
    if (k0 < 400) w = *(const float4*)(W_hh + (size_t)row * 400 + k0);
    else          w = *(const float4*)(W_ih + (size_t)row * 4);
    unsigned short* dst = Wl + c * WROW + k0;
    dst[0] = f2bf(w.x); dst[1] = f2bf(w.y); dst[2] = f2bf(w.z); dst[3] = f2bf(w.w);
  }
  for (int idx = tid; idx < NCOL * (WROW - KTOT); idx += 640) {
    int c = idx / (WROW - KTOT), kk = KTOT + idx % (WROW - KTOT);
    Wl[c * WROW + kk] = 0;
  }
  if (tid < NCOL) {
    int gt = tid / HU, u = tid % HU;
    bias_l[tid] = b_enc[gt * 400 + hbase + u];
  }
  cstate[tid] = 0.f;
  // x_0 into parity-0 buffer (h region zero from host-side memset)
  if (n == 0 && tid < BPG) {
    float4 xv = *(const float4*)(x + (size_t)(bbase + tid) * T_STEPS * 4);
    unsigned short* d = hbuf + (size_t)(bbase + tid) * HROW + 400;
    d[0] = f2bf(xv.x); d[1] = f2bf(xv.y); d[2] = f2bf(xv.z); d[3] = f2bf(xv.w);
  }
  __syncthreads();
  int* ctr = flags + g * 16;   // one aggregated counter per group (64B stride)
  if (tid == 0) {
    __threadfence();
    __hip_atomic_fetch_add(ctr, 1, __ATOMIC_RELEASE, __HIP_MEMORY_SCOPE_AGENT);
  }

  const int wave = tid >> 6, lane = tid & 63;
  const int arow = lane & 15, kgrp = lane >> 4;
  const unsigned short* Bbase = Wl + (wave * 16 + arow) * WROW + kgrp * 8;
  const int bb = tid / HU, uu = tid - bb * HU;   // elementwise ownership

  for (int t = 0; t < T_STEPS; ++t) {
    const int p = t & 1;
    // prefetch next x (slice 0, lanes<16 of wave 0), hidden under poll
    float4 xn;
    const bool do_x = (n == 0) && (tid < BPG) && (t + 1 < T_STEPS);
    if (do_x) xn = *(const float4*)(x + ((size_t)(bbase + tid) * T_STEPS + (t + 1)) * 4);

    // --- wave 0 polls the aggregated counter; everyone else parks at barrier
    if (wave == 0) {
      const int target = HS * (t + 1);
      while (__hip_atomic_load(ctr, __ATOMIC_ACQUIRE, __HIP_MEMORY_SCOPE_AGENT) < target)
        __builtin_amdgcn_s_sleep(1);
    }
    __syncthreads();

    // --- GEMM: gates[16 batches x 160 cols] over K=416; wave w -> col tile w
    const unsigned short* Arow = hbuf + ((size_t)p * 128 + (bbase + arow)) * HROW + kgrp * 8;
    f32x4 acc = {0.f, 0.f, 0.f, 0.f};
#pragma unroll
    for (int kc = 0; kc < KCH; ++kc) {
      s16x8 a = *(const s16x8*)(Arow + kc * 32);
      s16x8 b = *(const s16x8*)(Bbase + kc * 32);
      acc = __builtin_amdgcn_mfma_f32_16x16x32_bf16(a, b, acc, 0, 0, 0);
    }
    {
      const int c = wave * 16 + arow;
#pragma unroll
      for (int r = 0; r < 4; ++r)
        gatesF[c * GPITCH + kgrp * 4 + r] = acc[r];
    }
    __syncthreads();

    // --- elementwise gate update; thread owns (batch bb, unit uu)
    {
      float gi = gatesF[uu * GPITCH + bb] + bias_l[uu];
      float gf = gatesF[(HU + uu) * GPITCH + bb] + bias_l[HU + uu];
      float gg = gatesF[(2 * HU + uu) * GPITCH + bb] + bias_l[2 * HU + uu];
      float go = gatesF[(3 * HU + uu) * GPITCH + bb] + bias_l[3 * HU + uu];
      float cn = sigm(gf) * cstate[tid] + sigm(gi) * tanh_f(gg);
      float hn = sigm(go) * tanh_f(cn);
      cstate[tid] = cn;
      hbuf[((size_t)(p ^ 1) * 128 + (bbase + bb)) * HROW + hbase + uu] = f2bf(hn);
      if (t == T_STEPS - 1) last_h[(size_t)(bbase + bb) * 400 + hbase + uu] = hn;
    }
    if (do_x) {
      unsigned short* d = hbuf + ((size_t)(p ^ 1) * 128 + (bbase + tid)) * HROW + 400;
      d[0] = f2bf(xn.x); d[1] = f2bf(xn.y); d[2] = f2bf(xn.z); d[3] = f2bf(xn.w);
    }
    __syncthreads();   // drains all waves' global stores (vmcnt 0 before barrier)
    if (tid == 0) {
      __threadfence();
      __hip_atomic_fetch_add(ctr, 1, __ATOMIC_RELEASE, __HIP_MEMORY_SCOPE_AGENT);
    }
  }
}

// ---------------------------------------------------------------------------
// Decoder input precompute: uw[b,t,16] = relu(x W_i2h^T + b_i2h) W_dec_ih^T + b_dec
// grid = 512, block = 256, 2 positions per thread.
// ---------------------------------------------------------------------------
__global__ __launch_bounds__(256) void uw_kernel(
    const float* __restrict__ x, const float* __restrict__ W_i2h,
    const float* __restrict__ b_i2h, const float* __restrict__ W_dec,
    const float* __restrict__ b_dec, float* __restrict__ uw)
{
  __shared__ float4 Wi[400];
  __shared__ float4 WdT[400][4];
  __shared__ float bi[400];
  __shared__ float bd[16];
  const int tid = threadIdx.x;
  for (int i = tid; i < 400; i += 256) {
    Wi[i] = *(const float4*)(W_i2h + (size_t)i * 4);
    bi[i] = b_i2h[i];
  }
  for (int i = tid; i < 6400; i += 256) {
    int gq = i & 15, hh = i >> 4;
    ((float*)&WdT[hh][0])[gq] = W_dec[(size_t)gq * 400 + hh];
  }
  if (tid < 16) bd[tid] = b_dec[tid];
  __syncthreads();

  const size_t base = ((size_t)blockIdx.x * 256 + tid) * 2;
  float4 xv0 = *(const float4*)(x + base * 4);
  float4 xv1 = *(const float4*)(x + base * 4 + 4);
  float a0[16], a1[16];
#pragma unroll
  for (int q = 0; q < 16; ++q) { a0[q] = bd[q]; a1[q] = bd[q]; }
  for (int hh = 0; hh < 400; ++hh) {
    float4 wv = Wi[hh];
    float bih = bi[hh];
    float u0 = fmaxf(wv.x * xv0.x + wv.y * xv0.y + wv.z * xv0.z + wv.w * xv0.w + bih, 0.f);
    float u1 = fmaxf(wv.x * xv1.x + wv.y * xv1.y + wv.z * xv1.z + wv.w * xv1.w + bih, 0.f);
#pragma unroll
    for (int q4 = 0; q4 < 4; ++q4) {
      float4 d = WdT[hh][q4];
      a0[q4 * 4 + 0] = fmaf(d.x, u0, a0[q4 * 4 + 0]);
      a0[q4 * 4 + 1] = fmaf(d.y, u0, a0[q4 * 4 + 1]);
      a0[q4 * 4 + 2] = fmaf(d.z, u0, a0[q4 * 4 + 2]);
      a0[q4 * 4 + 3] = fmaf(d.w, u0, a0[q4 * 4 + 3]);
      a1[q4 * 4 + 0] = fmaf(d.x, u1, a1[q4 * 4 + 0]);
      a1[q4 * 4 + 1] = fmaf(d.y, u1, a1[q4 * 4 + 1]);
      a1[q4 * 4 + 2] = fmaf(d.z, u1, a1[q4 * 4 + 2]);
      a1[q4 * 4 + 3] = fmaf(d.w, u1, a1[q4 * 4 + 3]);
    }
  }
  float4* o0 = (float4*)(uw + base * 16);
  float4* o1 = (float4*)(uw + base * 16 + 16);
#pragma unroll
  for (int q4 = 0; q4 < 4; ++q4) {
    o0[q4] = make_float4(a0[q4 * 4], a0[q4 * 4 + 1], a0[q4 * 4 + 2], a0[q4 * 4 + 3]);
    o1[q4] = make_float4(a1[q4 * 4], a1[q4 * 4 + 1], a1[q4 * 4 + 2], a1[q4 * 4 + 3]);
  }
}

// ---------------------------------------------------------------------------
// Head: mu, logvar, z, decoder h0. grid = 128 (one per batch), block = 64.
// ---------------------------------------------------------------------------
__global__ __launch_bounds__(64) void head_kernel(
    const float* __restrict__ last_h, const float* __restrict__ eps,
    const float* __restrict__ W_mu, const float* __restrict__ b_mu,
    const float* __restrict__ W_lv, const float* __restrict__ b_lv,
    const float* __restrict__ W_l2h, const float* __restrict__ b_l2h,
    float* __restrict__ out, float* __restrict__ hd0)
{
  const int b = blockIdx.x, tid = threadIdx.x;
  __shared__ float smu[20], slv[20], sz[20];
  const float4* h4 = (const float4*)(last_h + (size_t)b * 400);
  if (tid < 40) {
    const int o = tid % 20;
    const float4* w4 = (const float4*)((tid < 20 ? W_mu : W_lv) + (size_t)o * 400);
    float s = 0.f;
    for (int k = 0; k < 100; ++k) {
      float4 a = h4[k], w = w4[k];
      s += a.x * w.x + a.y * w.y + a.z * w.z + a.w * w.w;
    }
    if (tid < 20) { s += b_mu[o]; smu[o] = s; out[512 + b * 20 + o] = s; }
    else          { s += b_lv[o]; slv[o] = s; out[512 + 2560 + b * 20 + o] = s; }
  }
  __syncthreads();
  if (tid < 20) sz[tid] = smu[tid] + eps[b * 20 + tid] * __expf(0.5f * slv[tid]);
  __syncthreads();
  if (tid < 4) {
    float s = b_l2h[tid];
    for (int l = 0; l < 20; ++l) s += W_l2h[tid * 20 + l] * sz[l];
    hd0[b * 4 + tid] = s;
  }
}

// ---------------------------------------------------------------------------
// Decoder LSTM: hidden=4, 4 lanes per batch. grid = 8, block = 64.
// ---------------------------------------------------------------------------
__global__ __launch_bounds__(64) void dec_kernel(
    const float* __restrict__ uw, const float* __restrict__ hd0,
    const float* __restrict__ Whh, float* __restrict__ out)
{
  const int t0 = blockIdx.x * 64 + threadIdx.x;
  const int b = t0 >> 2, j = t0 & 3;
  float w[4][4];
#pragma unroll
  for (int gq = 0; gq < 4; ++gq)
#pragma unroll
    for (int k = 0; k < 4; ++k)
      w[gq][k] = Whh[(gq * 4 + j) * 4 + k];
  float h = hd0[b * 4 + j], c = 0.f;
  const float* up = uw + (size_t)b * T_STEPS * 16 + j;
  float n0 = up[0], n1 = up[4], n2 = up[8], n3 = up[12];
  for (int t = 0; t < T_STEPS; ++t) {
    float c0 = n0, c1 = n1, c2 = n2, c3 = n3;
    if (t + 1 < T_STEPS) {
      const float* u2 = up + (size_t)(t + 1) * 16;
      n0 = u2[0]; n1 = u2[4]; n2 = u2[8]; n3 = u2[12];
    }
    float h0 = __shfl(h, 0, 4), h1 = __shfl(h, 1, 4), h2 = __shfl(h, 2, 4), h3 = __shfl(h, 3, 4);
    c0 += w[0][0] * h0 + w[0][1] * h1 + w[0][2] * h2 + w[0][3] * h3;
    c1 += w[1][0] * h0 + w[1][1] * h1 + w[1][2] * h2 + w[1][3] * h3;
    c2 += w[2][0] * h0 + w[2][1] * h1 + w[2][2] * h2 + w[2][3] * h3;
    c3 += w[3][0] * h0 + w[3][1] * h1 + w[3][2] * h2 + w[3][3] * h3;
    c = sigm(c1) * c + sigm(c0) * tanh_f(c2);
    h = sigm(c3) * tanh_f(c);
  }
  out[b * 4 + j] = h;
}

// ---------------------------------------------------------------------------
// ws layout (bytes):
//   [0,      16384)  group counters (8 x 64B-strided ints, zeroed)
//   [16384,  229376) hbuf: 2 x 128 x 416 bf16 (zeroed)
//   [229376, 434176) last_h: 128 x 400 f32
//   [434176, 436224) hd0: 128 x 4 f32
//   [524288, 17301504) uw: 128 x 2048 x 16 f32
// ---------------------------------------------------------------------------
extern "C" void kernel_launch(void* const* d_in, const int* in_sizes, int n_in,
                              void* d_out, int out_size, void* d_ws, size_t ws_size,
                              hipStream_t stream)
{
  (void)in_sizes; (void)n_in; (void)out_size; (void)ws_size;
  const float* x        = (const float*)d_in[0];
  const float* eps      = (const float*)d_in[1];
  const float* W_enc_ih = (const float*)d_in[2];
  const float* W_enc_hh = (const float*)d_in[3];
  const float* b_enc    = (const float*)d_in[4];
  const float* W_mu     = (const float*)d_in[5];
  const float* b_mu     = (const float*)d_in[6];
  const float* W_lv     = (const float*)d_in[7];
  const float* b_lv     = (const float*)d_in[8];
  const float* W_l2h    = (const float*)d_in[9];
  const float* b_l2h    = (const float*)d_in[10];
  const float* W_i2h    = (const float*)d_in[11];
  const float* b_i2h    = (const float*)d_in[12];
  const float* W_dec_ih = (const float*)d_in[13];
  const float* W_dec_hh = (const float*)d_in[14];
  const float* b_dec    = (const float*)d_in[15];
  float* out = (float*)d_out;
  char* ws = (char*)d_ws;
  int* flags = (int*)ws;
  unsigned short* hbuf = (unsigned short*)(ws + 16384);
  float* last_h = (float*)(ws + 229376);
  float* hd0 = (float*)(ws + 434176);
  float* uw = (float*)(ws + 524288);

  static const int ENC_LDS = 149760;
  hipFuncSetAttribute((const void*)enc_kernel,
                      hipFuncAttributeMaxDynamicSharedMemorySize, ENC_LDS);

  hipMemsetAsync(ws, 0, 229376, stream);                      // counters + h_0 zeros
  uw_kernel<<<512, 256, 0, stream>>>(x, W_i2h, b_i2h, W_dec_ih, b_dec, uw);
  enc_kernel<<<80, 640, ENC_LDS, stream>>>(x, W_enc_hh, W_enc_ih, b_enc, hbuf, last_h, flags);
  head_kernel<<<128, 64, 0, stream>>>(last_h, eps, W_mu, b_mu, W_lv, b_lv, W_l2h, b_l2h, out, hd0);
  dec_kernel<<<8, 64, 0, stream>>>(uw, hd0, W_dec_hh, out);
}